// Round 1
// baseline (101.276 us; speedup 1.0000x reference)
//
#include <hip/hip_runtime.h>
#include <math.h>

// DVS forward: per-batch 6x6 normal-equation build + solve.
// B=64, image 512x640, border 5 -> interior 502x630.

namespace {
constexpr int HI  = 512;
constexpr int WI  = 640;
constexpr int BRD = 5;
constexpr int SSTR = 12;          // row strips per batch
constexpr int RPS  = 42;          // rows per strip (12*42=504 >= 502)
constexpr float PXc = 600.0f, PYc = 600.0f, U0c = 320.0f, V0c = 256.0f;
constexpr float F1 = 2047.0f / 8418.0f;
constexpr float F2 = 913.0f  / 8418.0f;
constexpr float F3 = 112.0f  / 8418.0f;
}

__global__ __launch_bounds__(640) void dvs_partial(
    const float* __restrict__ Is, const float* __restrict__ Ids,
    const float* __restrict__ Zinv, float* __restrict__ ws)
{
    const int strip = blockIdx.x;
    const int b     = blockIdx.y;
    const int tid   = threadIdx.x;              // column index 0..639
    const int r0 = BRD + strip * RPS;
    const int r1 = min(r0 + RPS, HI - BRD);     // exclusive
    const size_t ofs = (size_t)b * HI * WI;
    const float* __restrict__ Ib = Is   + ofs;
    const float* __restrict__ Db = Ids  + ofs;
    const float* __restrict__ Zb = Zinv + ofs;

    __shared__ float buf[4][WI];                // circular 4-row Ids buffer
    __shared__ float red[10][28];               // per-wave partials (padded)

    const bool act = (tid >= BRD) && (tid < WI - BRD);
    const float x  = ((float)tid - U0c) * (1.0f / PXc);

    float w0=0.f,w1=0.f,w2=0.f,w3=0.f,w4=0.f,w5=0.f,w6=0.f;
    float acc[27];
#pragma unroll
    for (int k = 0; k < 27; ++k) acc[k] = 0.0f;

    for (int nr = r0 - 3; nr < r1 + 3; ++nr) {
        const float v = Db[nr * WI + tid];      // one global read per Ids elem
        __syncthreads();                        // protect buf slot from prev readers
        buf[nr & 3][tid] = v;
        w0 = w1; w1 = w2; w2 = w3; w3 = w4; w4 = w5; w5 = w6; w6 = v;
        __syncthreads();
        const int rc = nr - 3;                  // center row for this iteration
        if (rc >= r0 && act) {
            const float* __restrict__ row = buf[rc & 3];
            const float Ixv = (F1 * (row[tid+1] - row[tid-1]) +
                               F2 * (row[tid+2] - row[tid-2]) +
                               F3 * (row[tid+3] - row[tid-3])) * PXc;
            const float Iyv = (F1 * (w4 - w2) +
                               F2 * (w5 - w1) +
                               F3 * (w6 - w0)) * PYc;
            const float y  = ((float)rc - V0c) * (1.0f / PYc);
            const float Z  = Zb[rc * WI + tid];
            const float e  = Ib[rc * WI + tid] - w3;   // w3 == Ids[rc][tid]
            const float xy = x * y;
            float L[6];
            L[0] = Ixv * Z;
            L[1] = Iyv * Z;
            L[2] = -(x * Ixv + y * Iyv) * Z;
            L[3] = -Ixv * xy - (1.0f + y * y) * Iyv;
            L[4] = (1.0f + x * x) * Ixv + Iyv * xy;
            L[5] = Iyv * x - Ixv * y;
            int k = 0;
#pragma unroll
            for (int i = 0; i < 6; ++i)
#pragma unroll
                for (int j = i; j < 6; ++j)
                    acc[k++] += L[i] * L[j];
#pragma unroll
            for (int i = 0; i < 6; ++i) acc[21 + i] += L[i] * e;
        }
    }

    // deterministic block reduction: wave shfl tree, then one pass over waves
    const int lane = tid & 63;
    const int wv   = tid >> 6;
#pragma unroll
    for (int k = 0; k < 27; ++k) {
        float v = acc[k];
        v += __shfl_xor(v, 1);
        v += __shfl_xor(v, 2);
        v += __shfl_xor(v, 4);
        v += __shfl_xor(v, 8);
        v += __shfl_xor(v, 16);
        v += __shfl_xor(v, 32);
        if (lane == 0) red[wv][k] = v;
    }
    __syncthreads();
    if (tid < 27) {
        float s = 0.0f;
#pragma unroll
        for (int q = 0; q < 10; ++q) s += red[q][tid];
        ws[((size_t)b * SSTR + strip) * 27 + tid] = s;
    }
}

__global__ void dvs_solve(const float* __restrict__ ws,
                          const float* __restrict__ mu,
                          float* __restrict__ out, int B)
{
    const int b = blockIdx.x * blockDim.x + threadIdx.x;
    if (b >= B) return;

    double a[27];
#pragma unroll
    for (int k = 0; k < 27; ++k) a[k] = 0.0;
    for (int s = 0; s < SSTR; ++s) {
        const float* p = ws + ((size_t)b * SSTR + s) * 27;
#pragma unroll
        for (int k = 0; k < 27; ++k) a[k] += (double)p[k];
    }

    double A[6][7];
    int k = 0;
    for (int i = 0; i < 6; ++i)
        for (int j = i; j < 6; ++j) { A[i][j] = a[k]; A[j][i] = a[k]; ++k; }
    const double dm = 1.0 + (double)mu[b];
    for (int i = 0; i < 6; ++i) { A[i][i] *= dm; A[i][6] = a[21 + i]; }

    // Gaussian elimination with partial pivoting (6x6, per-thread)
    for (int col = 0; col < 6; ++col) {
        int p = col; double best = fabs(A[col][col]);
        for (int r = col + 1; r < 6; ++r) {
            double vv = fabs(A[r][col]);
            if (vv > best) { best = vv; p = r; }
        }
        if (p != col) {
            for (int cc = col; cc < 7; ++cc) {
                double t = A[col][cc]; A[col][cc] = A[p][cc]; A[p][cc] = t;
            }
        }
        const double inv = 1.0 / A[col][col];
        for (int r = col + 1; r < 6; ++r) {
            const double f = A[r][col] * inv;
            for (int cc = col + 1; cc < 7; ++cc) A[r][cc] -= f * A[col][cc];
        }
    }
    double xs[6];
    for (int i = 5; i >= 0; --i) {
        double s = A[i][6];
        for (int j = i + 1; j < 6; ++j) s -= A[i][j] * xs[j];
        xs[i] = s / A[i][i];
    }
    for (int i = 0; i < 6; ++i) out[b * 6 + i] = (float)(-xs[i]);
}

extern "C" void kernel_launch(void* const* d_in, const int* in_sizes, int n_in,
                              void* d_out, int out_size, void* d_ws, size_t ws_size,
                              hipStream_t stream)
{
    const float* Is   = (const float*)d_in[0];
    const float* Ids  = (const float*)d_in[1];
    const float* Zinv = (const float*)d_in[2];
    const float* mu   = (const float*)d_in[3];
    const int B = in_sizes[3];
    float* out = (float*)d_out;
    float* ws  = (float*)d_ws;

    dim3 grid(SSTR, B);
    dvs_partial<<<grid, dim3(640), 0, stream>>>(Is, Ids, Zinv, ws);
    const int tb = 64;
    dvs_solve<<<(B + tb - 1) / tb, tb, 0, stream>>>(ws, mu, out, B);
}

// Round 2
// 96.745 us; speedup vs baseline: 1.0468x; 1.0468x over previous
//
#include <hip/hip_runtime.h>
#include <math.h>

// DVS forward: per-batch 6x6 normal-equation build + solve.
// B=64, image 512x640, border 5 -> interior rows [5,507), cols [5,635).
// Wave-autonomous streaming: no __syncthreads in the hot loop.
// Each wave: one (batch, column-segment, row-strip). Lane = 4 columns (float4).
// Vertical 7-tap from a register rolling window (unroll-8 rotation, all static
// indices); horizontal 7-tap via 6 __shfl from neighbor lanes.

namespace {
constexpr int HI = 512, WI = 640, BRD = 5;
constexpr int STRIPS = 16, RPS = 32, SEGS = 3, PART = SEGS * STRIPS; // 48
constexpr float PXc = 600.0f, PYc = 600.0f, U0c = 320.0f, V0c = 256.0f;
constexpr float F1 = 2047.0f / 8418.0f;
constexpr float F2 = 913.0f  / 8418.0f;
constexpr float F3 = 112.0f  / 8418.0f;
}

__device__ __forceinline__ float elem(const float4 v, int q) {
    return q == 0 ? v.x : (q == 1 ? v.y : (q == 2 ? v.z : v.w));
}

__global__ __launch_bounds__(256) void dvs_partial(
    const float* __restrict__ Is, const float* __restrict__ Ids,
    const float* __restrict__ Zinv, float* __restrict__ ws)
{
    const int wid  = (blockIdx.x * 256 + threadIdx.x) >> 6;
    const int lane = threadIdx.x & 63;
    const int b     = wid / PART;
    const int rem   = wid - b * PART;
    const int seg   = rem / STRIPS;
    const int strip = rem - seg * STRIPS;
    const int r0 = BRD + strip * RPS;
    const int r1 = min(r0 + RPS, HI - BRD);          // exclusive
    // segments: float4-aligned bases; ownership is 4-aligned except img edges
    const int base = (seg == 0) ? 0   : ((seg == 1) ? 200 : 384);
    const int lo   = (seg == 0) ? 5   : ((seg == 1) ? 252 : 452);
    const int hi   = (seg == 0) ? 252 : ((seg == 1) ? 452 : 635);
    const int c0 = base + (lane << 2);
    const size_t ofs = (size_t)b * (HI * WI);
    const float* __restrict__ Ib = Is   + ofs;
    const float* __restrict__ Db = Ids  + ofs;
    const float* __restrict__ Zb = Zinv + ofs;

    const bool anyOwn = (c0 + 3 >= lo) && (c0 < hi);
    float msk[4], xk[4];
#pragma unroll
    for (int q = 0; q < 4; ++q) {
        const int c = c0 + q;
        msk[q] = (c >= lo && c < hi) ? 1.0f : 0.0f;
        xk[q]  = ((float)c - U0c) * (1.0f / PXc);
    }

    // rolling Ids window: win[(k+j)&7] = row rc-3+j at inner step k
    float4 win[8];
#pragma unroll
    for (int i = 0; i < 7; ++i)
        win[i] = *(const float4*)(Db + (r0 - 3 + i) * WI + c0);
    win[7] = win[0];                                  // dead init
    float4 isv[2], zv[2];
    isv[0] = isv[1] = zv[0] = zv[1] = make_float4(0.f, 0.f, 0.f, 0.f);
    if (anyOwn) {
        isv[0] = *(const float4*)(Ib + r0 * WI + c0);
        zv[0]  = *(const float4*)(Zb + r0 * WI + c0);
    }

    float acc[27];
#pragma unroll
    for (int t = 0; t < 27; ++t) acc[t] = 0.0f;

    for (int r = r0; r < r1; r += 8) {
#pragma unroll
        for (int k = 0; k < 8; ++k) {
            const int rc = r + k;
            // prefetch row rc+4 of Ids into the slot freed by this step
            const int rpf = min(rc + 4, HI - 3);
            win[(k + 7) & 7] = *(const float4*)(Db + rpf * WI + c0);
            // prefetch Is/Zinv for the next center row
            const int rn = min(rc + 1, r1 - 1);
            if (anyOwn) {
                isv[(k + 1) & 1] = *(const float4*)(Ib + rn * WI + c0);
                zv[(k + 1) & 1]  = *(const float4*)(Zb + rn * WI + c0);
            }
            if (rc < r1) {                            // wave-uniform guard
                const float4 a0 = win[k & 7],       a1 = win[(k + 1) & 7],
                             a2 = win[(k + 2) & 7], ct = win[(k + 3) & 7],
                             a4 = win[(k + 4) & 7], a5 = win[(k + 5) & 7],
                             a6 = win[(k + 6) & 7];
                const int lm = (lane + 63) & 63, lp = (lane + 1) & 63;
                const float hl1 = __shfl(ct.w, lm);   // col c0-1
                const float hl2 = __shfl(ct.z, lm);   // col c0-2
                const float hl3 = __shfl(ct.y, lm);   // col c0-3
                const float hr1 = __shfl(ct.x, lp);   // col c0+4
                const float hr2 = __shfl(ct.y, lp);   // col c0+5
                const float hr3 = __shfl(ct.z, lp);   // col c0+6
                const float h[10] = {hl3, hl2, hl1, ct.x, ct.y, ct.z, ct.w,
                                     hr1, hr2, hr3};
                const float yv = ((float)rc - V0c) * (1.0f / PYc);
                const float4 isV = isv[k & 1], zV = zv[k & 1];
#pragma unroll
                for (int q = 0; q < 4; ++q) {
                    const float Ix = (F1 * (h[q + 4] - h[q + 2]) +
                                      F2 * (h[q + 5] - h[q + 1]) +
                                      F3 * (h[q + 6] - h[q])) * PXc * msk[q];
                    const float Iy = (F1 * (elem(a4, q) - elem(a2, q)) +
                                      F2 * (elem(a5, q) - elem(a1, q)) +
                                      F3 * (elem(a6, q) - elem(a0, q))) * PYc * msk[q];
                    const float Z  = elem(zV, q);
                    const float e  = elem(isV, q) - elem(ct, q);
                    const float x  = xk[q], xy = x * yv;
                    float L[6];
                    L[0] = Ix * Z;
                    L[1] = Iy * Z;
                    L[2] = -(x * Ix + yv * Iy) * Z;
                    L[3] = -Ix * xy - (1.0f + yv * yv) * Iy;
                    L[4] = (1.0f + x * x) * Ix + Iy * xy;
                    L[5] = Iy * x - Ix * yv;
                    int t = 0;
#pragma unroll
                    for (int i = 0; i < 6; ++i)
#pragma unroll
                        for (int j = i; j < 6; ++j)
                            acc[t++] += L[i] * L[j];
#pragma unroll
                    for (int i = 0; i < 6; ++i) acc[21 + i] += L[i] * e;
                }
            }
        }
    }

    // wave butterfly reduce (deterministic), then lanes 0..26 store
#pragma unroll
    for (int t = 0; t < 27; ++t) {
        float v = acc[t];
        v += __shfl_xor(v, 1);  v += __shfl_xor(v, 2);  v += __shfl_xor(v, 4);
        v += __shfl_xor(v, 8);  v += __shfl_xor(v, 16); v += __shfl_xor(v, 32);
        acc[t] = v;
    }
    float outv = acc[0];
#pragma unroll
    for (int t = 1; t < 27; ++t) if (lane == t) outv = acc[t];
    if (lane < 27) ws[(size_t)wid * 27 + lane] = outv;
}

__global__ void dvs_solve(const float* __restrict__ ws,
                          const float* __restrict__ mu,
                          float* __restrict__ out, int B)
{
    const int b = blockIdx.x * blockDim.x + threadIdx.x;
    if (b >= B) return;

    double a[27];
#pragma unroll
    for (int k = 0; k < 27; ++k) a[k] = 0.0;
    for (int s = 0; s < PART; ++s) {
        const float* p = ws + ((size_t)b * PART + s) * 27;
#pragma unroll
        for (int k = 0; k < 27; ++k) a[k] += (double)p[k];
    }

    double A[6][7];
    int k = 0;
    for (int i = 0; i < 6; ++i)
        for (int j = i; j < 6; ++j) { A[i][j] = a[k]; A[j][i] = a[k]; ++k; }
    const double dm = 1.0 + (double)mu[b];
    for (int i = 0; i < 6; ++i) { A[i][i] *= dm; A[i][6] = a[21 + i]; }

    for (int col = 0; col < 6; ++col) {
        int p = col; double best = fabs(A[col][col]);
        for (int r = col + 1; r < 6; ++r) {
            double vv = fabs(A[r][col]);
            if (vv > best) { best = vv; p = r; }
        }
        if (p != col) {
            for (int cc = col; cc < 7; ++cc) {
                double t = A[col][cc]; A[col][cc] = A[p][cc]; A[p][cc] = t;
            }
        }
        const double inv = 1.0 / A[col][col];
        for (int r = col + 1; r < 6; ++r) {
            const double f = A[r][col] * inv;
            for (int cc = col + 1; cc < 7; ++cc) A[r][cc] -= f * A[col][cc];
        }
    }
    double xs[6];
    for (int i = 5; i >= 0; --i) {
        double s = A[i][6];
        for (int j = i + 1; j < 6; ++j) s -= A[i][j] * xs[j];
        xs[i] = s / A[i][i];
    }
    for (int i = 0; i < 6; ++i) out[b * 6 + i] = (float)(-xs[i]);
}

extern "C" void kernel_launch(void* const* d_in, const int* in_sizes, int n_in,
                              void* d_out, int out_size, void* d_ws, size_t ws_size,
                              hipStream_t stream)
{
    const float* Is   = (const float*)d_in[0];
    const float* Ids  = (const float*)d_in[1];
    const float* Zinv = (const float*)d_in[2];
    const float* mu   = (const float*)d_in[3];
    const int B = in_sizes[3];
    float* out = (float*)d_out;
    float* ws  = (float*)d_ws;

    const int total_waves = B * PART;             // 3072
    const int blocks = total_waves / 4;           // 256 threads = 4 waves
    dvs_partial<<<blocks, 256, 0, stream>>>(Is, Ids, Zinv, ws);
    dvs_solve<<<1, 64, 0, stream>>>(ws, mu, out, B);
}

// Round 3
// 70.304 us; speedup vs baseline: 1.4405x; 1.3761x over previous
//
#include <hip/hip_runtime.h>
#include <math.h>

// DVS forward: per-batch 6x6 normal-equation build + solve.
// B=64, image 512x640, border 5 -> interior rows [5,507), cols [5,635).
// R2: latency-hiding via tile-parallel waves. Each wave owns a (batch, seg,
// 4-row tile); its 18 float4 loads (10 Ids rows + 4 Is + 4 Zinv) are all
// address-independent and issued up front, then 4 statically-unrolled row
// computations. 24576 waves total. Block (4 waves) LDS-reduces to one
// 27-float partial.

namespace {
constexpr int HI = 512, WI = 640, BRD = 5;
constexpr int RPT = 4;                 // rows per wave-tile
constexpr int TILES = 128;             // ceil(502/4) padded to /4 blocks
constexpr int TG = TILES / 4;          // tile-groups (blocks) per (b,seg) = 32
constexpr int SEGS = 3;
constexpr int BLK_PER_B = SEGS * TG;   // 96 partials per batch
constexpr float PXc = 600.0f, PYc = 600.0f, U0c = 320.0f, V0c = 256.0f;
constexpr float G1 = 2047.0f / 8418.0f * 600.0f;   // F*PX (PX==PY)
constexpr float G2 = 913.0f  / 8418.0f * 600.0f;
constexpr float G3 = 112.0f  / 8418.0f * 600.0f;
}

__device__ __forceinline__ float elem(const float4 v, int q) {
    return q == 0 ? v.x : (q == 1 ? v.y : (q == 2 ? v.z : v.w));
}

__global__ __launch_bounds__(256) void dvs_partial(
    const float* __restrict__ Is, const float* __restrict__ Ids,
    const float* __restrict__ Zinv, float* __restrict__ ws)
{
    const int tid  = threadIdx.x;
    const int lane = tid & 63;
    const int wv   = tid >> 6;
    // block -> (b, seg, tilegroup); wave wv -> tile = tg*4 + wv
    const int b   = blockIdx.x / BLK_PER_B;
    const int rem = blockIdx.x - b * BLK_PER_B;
    const int seg = rem / TG;
    const int tg  = rem - seg * TG;
    const int tile = tg * 4 + wv;
    const int r0 = BRD + tile * RPT;             // center rows r0..r0+3 (masked)

    const int base = (seg == 0) ? 0   : ((seg == 1) ? 200 : 384);
    const int lo   = (seg == 0) ? 5   : ((seg == 1) ? 252 : 452);
    const int hi   = (seg == 0) ? 252 : ((seg == 1) ? 452 : 635);
    const int c0 = base + (lane << 2);

    const size_t ofs = (size_t)b * (HI * WI);
    const float* __restrict__ Ib = Is   + ofs;
    const float* __restrict__ Db = Ids  + ofs;
    const float* __restrict__ Zb = Zinv + ofs;

    float msk[4], xk[4], opx[4];
#pragma unroll
    for (int q = 0; q < 4; ++q) {
        const int c = c0 + q;
        msk[q] = (c >= lo && c < hi) ? 1.0f : 0.0f;
        xk[q]  = ((float)c - U0c) * (1.0f / PXc);
        opx[q] = 1.0f + xk[q] * xk[q];
    }

    // ---- issue ALL tile loads up front (independent addresses) ----
    float4 win[10];
#pragma unroll
    for (int j = 0; j < 10; ++j) {
        const int rr = min(r0 - 3 + j, HI - 1);
        win[j] = *(const float4*)(Db + rr * WI + c0);
    }
    float4 isv[4], zvv[4];
#pragma unroll
    for (int k = 0; k < RPT; ++k) {
        const int rr = min(r0 + k, HI - 1);
        isv[k] = *(const float4*)(Ib + rr * WI + c0);
        zvv[k] = *(const float4*)(Zb + rr * WI + c0);
    }

    float acc[27];
#pragma unroll
    for (int t = 0; t < 27; ++t) acc[t] = 0.0f;

    const int lm = (lane + 63) & 63, lp = (lane + 1) & 63;

#pragma unroll
    for (int k = 0; k < RPT; ++k) {
        const int rc = r0 + k;
        const float rmk = (rc < HI - BRD) ? 1.0f : 0.0f;
        const float4 a0 = win[k], a1 = win[k + 1], a2 = win[k + 2],
                     ct = win[k + 3], a4 = win[k + 4], a5 = win[k + 5],
                     a6 = win[k + 6];
        const float hl1 = __shfl(ct.w, lm);   // col c0-1
        const float hl2 = __shfl(ct.z, lm);   // col c0-2
        const float hl3 = __shfl(ct.y, lm);   // col c0-3
        const float hr1 = __shfl(ct.x, lp);   // col c0+4
        const float hr2 = __shfl(ct.y, lp);   // col c0+5
        const float hr3 = __shfl(ct.z, lp);   // col c0+6
        const float h[10] = {hl3, hl2, hl1, ct.x, ct.y, ct.z, ct.w,
                             hr1, hr2, hr3};
        const float yv  = ((float)rc - V0c) * (1.0f / PYc);
        const float opy = 1.0f + yv * yv;
        const float4 isV = isv[k], zV = zvv[k];
#pragma unroll
        for (int q = 0; q < 4; ++q) {
            const float m  = msk[q] * rmk;
            const float Ix = (G1 * (h[q + 4] - h[q + 2]) +
                              G2 * (h[q + 5] - h[q + 1]) +
                              G3 * (h[q + 6] - h[q])) * m;
            const float Iy = (G1 * (elem(a4, q) - elem(a2, q)) +
                              G2 * (elem(a5, q) - elem(a1, q)) +
                              G3 * (elem(a6, q) - elem(a0, q))) * m;
            const float Z  = elem(zV, q);
            const float e  = elem(isV, q) - elem(ct, q);
            const float x  = xk[q], xy = x * yv;
            float L[6];
            L[0] = Ix * Z;
            L[1] = Iy * Z;
            L[2] = -(x * Ix + yv * Iy) * Z;
            L[3] = -Ix * xy - opy * Iy;
            L[4] = opx[q] * Ix + Iy * xy;
            L[5] = Iy * x - Ix * yv;
            int t = 0;
#pragma unroll
            for (int i = 0; i < 6; ++i)
#pragma unroll
                for (int j = i; j < 6; ++j)
                    acc[t++] += L[i] * L[j];
#pragma unroll
            for (int i = 0; i < 6; ++i) acc[21 + i] += L[i] * e;
        }
    }

    // wave butterfly reduce (deterministic)
#pragma unroll
    for (int t = 0; t < 27; ++t) {
        float v = acc[t];
        v += __shfl_xor(v, 1);  v += __shfl_xor(v, 2);  v += __shfl_xor(v, 4);
        v += __shfl_xor(v, 8);  v += __shfl_xor(v, 16); v += __shfl_xor(v, 32);
        acc[t] = v;
    }
    float outv = acc[0];
#pragma unroll
    for (int t = 1; t < 27; ++t) if (lane == t) outv = acc[t];

    __shared__ float red[4][28];
    if (lane < 27) red[wv][lane] = outv;
    __syncthreads();
    if (tid < 27) {
        float s = red[0][tid] + red[1][tid] + red[2][tid] + red[3][tid];
        ws[(size_t)blockIdx.x * 27 + tid] = s;
    }
}

__global__ __launch_bounds__(128) void dvs_solve(
    const float* __restrict__ ws, const float* __restrict__ mu,
    float* __restrict__ out)
{
    const int b = blockIdx.x;
    __shared__ float sd[27][BLK_PER_B + 1];
    for (int i = threadIdx.x; i < BLK_PER_B * 27; i += 128) {
        const int s = i / 27, k = i - s * 27;
        sd[k][s] = ws[((size_t)b * BLK_PER_B + s) * 27 + k];
    }
    __syncthreads();
    __shared__ double hsum[27];
    if (threadIdx.x < 27) {
        double t = 0.0;
        for (int s = 0; s < BLK_PER_B; ++s) t += (double)sd[threadIdx.x][s];
        hsum[threadIdx.x] = t;
    }
    __syncthreads();
    if (threadIdx.x == 0) {
        double A[6][7];
        int k = 0;
        for (int i = 0; i < 6; ++i)
            for (int j = i; j < 6; ++j) { A[i][j] = hsum[k]; A[j][i] = hsum[k]; ++k; }
        const double dm = 1.0 + (double)mu[b];
        for (int i = 0; i < 6; ++i) { A[i][i] *= dm; A[i][6] = hsum[21 + i]; }
        for (int col = 0; col < 6; ++col) {
            int p = col; double best = fabs(A[col][col]);
            for (int r = col + 1; r < 6; ++r) {
                const double vv = fabs(A[r][col]);
                if (vv > best) { best = vv; p = r; }
            }
            if (p != col)
                for (int cc = col; cc < 7; ++cc) {
                    const double t = A[col][cc]; A[col][cc] = A[p][cc]; A[p][cc] = t;
                }
            const double inv = 1.0 / A[col][col];
            for (int r = col + 1; r < 6; ++r) {
                const double f = A[r][col] * inv;
                for (int cc = col + 1; cc < 7; ++cc) A[r][cc] -= f * A[col][cc];
            }
        }
        double xs[6];
        for (int i = 5; i >= 0; --i) {
            double s = A[i][6];
            for (int j = i + 1; j < 6; ++j) s -= A[i][j] * xs[j];
            xs[i] = s / A[i][i];
        }
        for (int i = 0; i < 6; ++i) out[b * 6 + i] = (float)(-xs[i]);
    }
}

extern "C" void kernel_launch(void* const* d_in, const int* in_sizes, int n_in,
                              void* d_out, int out_size, void* d_ws, size_t ws_size,
                              hipStream_t stream)
{
    const float* Is   = (const float*)d_in[0];
    const float* Ids  = (const float*)d_in[1];
    const float* Zinv = (const float*)d_in[2];
    const float* mu   = (const float*)d_in[3];
    const int B = in_sizes[3];
    float* out = (float*)d_out;
    float* ws  = (float*)d_ws;

    dvs_partial<<<B * BLK_PER_B, 256, 0, stream>>>(Is, Ids, Zinv, ws);
    dvs_solve<<<B, 128, 0, stream>>>(ws, mu, out);
}